// Round 1
// baseline (229.949 us; speedup 1.0000x reference)
//
#include <hip/hip_runtime.h>

// Non-local block (dot-product variant), algebraically collapsed:
//   out_b = (I + A'_b) x_b + bias'_b
// with per-batch Gram G_b = x_b x_b^T (256x256) and x-independent U,V,...
//
// C=256 in-channels, CI=128 inter, N=4096 spatial, NB=4 batches.

#define CC   256
#define CIC  128
#define NSP  4096
#define NB   4

// workspace layout (float offsets)
#define NCHUNK   8
#define KC       512                       // 4096 / NCHUNK
#define OFF_P    0                         // [NCHUNK][NB][256][256] partial gram
#define OFF_G    (NCHUNK*NB*65536)         // 2097152
#define OFF_Q    (OFF_G + NB*65536)        // Q = U @ G_b
#define OFF_A    (OFF_Q + NB*65536)        // A = I + A'
#define OFF_U    (OFF_A + NB*65536)        // U = out_w @ g_w        [256,256]
#define OFF_V    (OFF_U + 65536)           // V = phi_w^T @ theta_w  [256,256]
#define OFF_S    (OFF_V + 65536)           // s_b row sums [NB][256]
#define OFF_U0   (OFF_S + NB*256)          // u0 = out_w @ g_b       [256]
#define OFF_WTB  (OFF_U0 + 256)            // wtb = phi_w^T theta_b  [256]
#define OFF_TPB  (OFF_WTB + 256)           // tpb = theta_w^T phi_b  [256]
#define OFF_US   (OFF_TPB + 256)           // U @ s_b   [NB][256]
#define OFF_VTS  (OFF_US + NB*256)         // V^T @ s_b [NB][256]
#define OFF_BIAS (OFF_VTS + NB*256)        // bias'_b   [NB][256]
#define OFF_SCAL (OFF_BIAS + NB*256)       // [0]=c0

#define LDSPAD 68   // k-major LDS row stride: 68*4B=272B, 16B aligned, spreads banks

// ---- shared GEMM helpers: 64x64 tile, 4x4 micro-tile, K staged 32 ----

// load [64 rows][32 k] from row-major src (row r at src + r*stride) into Ls[k][row]
__device__ __forceinline__ void stage_t(const float* __restrict__ src, int stride,
                                        float (*Ls)[LDSPAD], int t) {
  int r  = t >> 2;           // 0..63
  int ks = (t & 3) << 3;     // 0,8,16,24
  const float* p = src + r * stride + ks;
  float4 v0 = *(const float4*)p;
  float4 v1 = *(const float4*)(p + 4);
  Ls[ks + 0][r] = v0.x; Ls[ks + 1][r] = v0.y; Ls[ks + 2][r] = v0.z; Ls[ks + 3][r] = v0.w;
  Ls[ks + 4][r] = v1.x; Ls[ks + 5][r] = v1.y; Ls[ks + 6][r] = v1.z; Ls[ks + 7][r] = v1.w;
}

// load [32 k rows][64 cols] from row-major src (row k at src + k*stride) into Ls[k][col]
__device__ __forceinline__ void stage_n(const float* __restrict__ src, int stride,
                                        float (*Ls)[LDSPAD], int t) {
  int kk = t >> 3;           // 0..31
  int cs = (t & 7) << 3;     // 0..56
  const float* p = src + kk * stride + cs;
  float4 v0 = *(const float4*)p;
  float4 v1 = *(const float4*)(p + 4);
  *(float4*)&Ls[kk][cs]     = v0;
  *(float4*)&Ls[kk][cs + 4] = v1;
}

__device__ __forceinline__ void mac_tile(const float (*As)[LDSPAD],
                                         const float (*Bs)[LDSPAD],
                                         float acc[4][4], int tx, int ty) {
#pragma unroll
  for (int kk = 0; kk < 32; ++kk) {
    float4 a = *(const float4*)&As[kk][ty << 2];
    float4 b = *(const float4*)&Bs[kk][tx << 2];
    float av[4] = {a.x, a.y, a.z, a.w};
    float bv[4] = {b.x, b.y, b.z, b.w};
#pragma unroll
    for (int i = 0; i < 4; ++i)
#pragma unroll
      for (int j = 0; j < 4; ++j)
        acc[i][j] = fmaf(av[i], bv[j], acc[i][j]);
  }
}

// ---- K0: x-independent small matrices/vectors ----
__global__ __launch_bounds__(256) void k_small0(
    const float* __restrict__ g_w, const float* __restrict__ g_b,
    const float* __restrict__ theta_w, const float* __restrict__ theta_b,
    const float* __restrict__ phi_w, const float* __restrict__ phi_b,
    const float* __restrict__ out_w, float* __restrict__ ws) {
  int bid = blockIdx.x, t = threadIdx.x;
  if (bid < 256) {                 // U[i][j] = sum_k out_w[i][k] g_w[k][j]
    int i = bid;
    float acc = 0.f;
    for (int k = 0; k < CIC; ++k) acc = fmaf(out_w[i * CIC + k], g_w[k * CC + t], acc);
    ws[OFF_U + i * CC + t] = acc;
  } else if (bid < 512) {          // V[i][j] = sum_k phi_w[k][i] theta_w[k][j]
    int i = bid - 256;
    float acc = 0.f;
    for (int k = 0; k < CIC; ++k) acc = fmaf(phi_w[k * CC + i], theta_w[k * CC + t], acc);
    ws[OFF_V + i * CC + t] = acc;
  } else {                         // vectors
    float a0 = 0.f, a1 = 0.f, a2 = 0.f;
    for (int k = 0; k < CIC; ++k) {
      a0 = fmaf(out_w[t * CIC + k], g_b[k], a0);
      a1 = fmaf(phi_w[k * CC + t], theta_b[k], a1);
      a2 = fmaf(theta_w[k * CC + t], phi_b[k], a2);
    }
    ws[OFF_U0 + t]  = a0;
    ws[OFF_WTB + t] = a1;
    ws[OFF_TPB + t] = a2;
    if (t == 0) {
      float c = 0.f;
      for (int k = 0; k < CIC; ++k) c = fmaf(phi_b[k], theta_b[k], c);
      ws[OFF_SCAL] = c;
    }
  }
}

// ---- row sums s[b][c] = sum_p x[b][c][p] ----
__global__ __launch_bounds__(64) void k_rowsum(const float* __restrict__ x,
                                               float* __restrict__ ws) {
  int bid = blockIdx.x;            // b*256 + row
  int t = threadIdx.x;
  const float* p = x + (size_t)bid * NSP;
  float acc = 0.f;
  for (int q = t; q < NSP; q += 64) acc += p[q];
#pragma unroll
  for (int off = 32; off > 0; off >>= 1) acc += __shfl_down(acc, off);
  if (t == 0) ws[OFF_S + bid] = acc;
}

// ---- split-K Gram partials: P[c][b] += x_tile_i . x_tile_j^T ----
__global__ __launch_bounds__(256) void k_gram(const float* __restrict__ x,
                                              float* __restrict__ ws) {
  __shared__ float As[32][LDSPAD], Bs[32][LDSPAD];
  int t = threadIdx.x, bid = blockIdx.x;
  int b = bid & 3;
  int c = (bid >> 2) & 7;
  int tile = bid >> 5;             // 0..15
  int ti = tile & 3, tj = tile >> 2;
  const float* xb = x + (size_t)b * CC * NSP;
  const float* Abase = xb + (ti * 64) * NSP + c * KC;
  const float* Bbase = xb + (tj * 64) * NSP + c * KC;
  float acc[4][4] = {};
  int tx = t & 15, ty = t >> 4;
  for (int k0 = 0; k0 < KC; k0 += 32) {
    stage_t(Abase + k0, NSP, As, t);
    stage_t(Bbase + k0, NSP, Bs, t);
    __syncthreads();
    mac_tile(As, Bs, acc, tx, ty);
    __syncthreads();
  }
  float* P = ws + OFF_P + (size_t)(c * 4 + b) * 65536;
#pragma unroll
  for (int i = 0; i < 4; ++i)
#pragma unroll
    for (int j = 0; j < 4; ++j)
      P[(ti * 64 + ty * 4 + i) * CC + (tj * 64 + tx * 4 + j)] = acc[i][j];
}

// ---- reduce Gram partials ----
__global__ __launch_bounds__(256) void k_gsum(float* __restrict__ ws) {
  int idx = blockIdx.x * 256 + threadIdx.x;   // 0..262143 over [b][i][j]
  float a = 0.f;
#pragma unroll
  for (int c = 0; c < NCHUNK; ++c) a += ws[OFF_P + c * (NB * 65536) + idx];
  ws[OFF_G + idx] = a;
}

// ---- Q_b = U @ G_b ----
__global__ __launch_bounds__(256) void k_q(float* __restrict__ ws) {
  __shared__ float As[32][LDSPAD], Bs[32][LDSPAD];
  int t = threadIdx.x, bid = blockIdx.x;
  int b = bid & 3, tj = (bid >> 2) & 3, ti = bid >> 4;
  const float* U = ws + OFF_U;
  const float* G = ws + OFF_G + b * 65536;
  float acc[4][4] = {};
  int tx = t & 15, ty = t >> 4;
  for (int k0 = 0; k0 < 256; k0 += 32) {
    stage_t(U + (ti * 64) * CC + k0, CC, As, t);
    stage_n(G + k0 * CC + tj * 64, CC, Bs, t);
    __syncthreads();
    mac_tile(As, Bs, acc, tx, ty);
    __syncthreads();
  }
  float* Q = ws + OFF_Q + b * 65536;
#pragma unroll
  for (int i = 0; i < 4; ++i)
#pragma unroll
    for (int j = 0; j < 4; ++j)
      Q[(ti * 64 + ty * 4 + i) * CC + (tj * 64 + tx * 4 + j)] = acc[i][j];
}

// ---- per-batch vectors: Us, Vts, swtb, bias' ----
__global__ __launch_bounds__(256) void k_vec(float* __restrict__ ws,
                                             const float* __restrict__ out_b) {
  __shared__ float sL[256], wtbL[256], red[256];
  int b = blockIdx.x, t = threadIdx.x;
  sL[t]   = ws[OFF_S + b * 256 + t];
  wtbL[t] = ws[OFF_WTB + t];
  __syncthreads();
  float us = 0.f, vts = 0.f;
  const float* U = ws + OFF_U;
  const float* V = ws + OFF_V;
  for (int k = 0; k < 256; ++k) {
    us  = fmaf(U[t * 256 + k], sL[k], us);
    vts = fmaf(V[k * 256 + t], sL[k], vts);
  }
  red[t] = sL[t] * wtbL[t];
  __syncthreads();
  for (int st = 128; st > 0; st >>= 1) {
    if (t < st) red[t] += red[t + st];
    __syncthreads();
  }
  float swtb = red[0];
  float c0 = ws[OFF_SCAL];
  const float* Q = ws + OFF_Q + b * 65536;
  float qrow = 0.f;
  for (int k = 0; k < 256; ++k) qrow = fmaf(Q[t * 256 + k], wtbL[k], qrow);
  float u0 = ws[OFF_U0 + t];
  const float inv = 1.0f / 4096.0f;
  float biasv = (qrow + u0 * swtb + (us + 4096.0f * u0) * c0) * inv + out_b[t];
  ws[OFF_US + b * 256 + t]   = us;
  ws[OFF_VTS + b * 256 + t]  = vts;
  ws[OFF_BIAS + b * 256 + t] = biasv;
}

// ---- A_b = I + (Q_b V + u0 (V^T s)^T + (Us + N u0) tpb^T)/N ----
__global__ __launch_bounds__(256) void k_a(float* __restrict__ ws) {
  __shared__ float As[32][LDSPAD], Bs[32][LDSPAD];
  int t = threadIdx.x, bid = blockIdx.x;
  int b = bid & 3, tj = (bid >> 2) & 3, ti = bid >> 4;
  const float* Q = ws + OFF_Q + b * 65536;
  const float* V = ws + OFF_V;
  float acc[4][4] = {};
  int tx = t & 15, ty = t >> 4;
  for (int k0 = 0; k0 < 256; k0 += 32) {
    stage_t(Q + (ti * 64) * CC + k0, CC, As, t);
    stage_n(V + k0 * CC + tj * 64, CC, Bs, t);
    __syncthreads();
    mac_tile(As, Bs, acc, tx, ty);
    __syncthreads();
  }
  float* A = ws + OFF_A + b * 65536;
  const float inv = 1.0f / 4096.0f;
#pragma unroll
  for (int i = 0; i < 4; ++i) {
    int ii = ti * 64 + ty * 4 + i;
    float u0 = ws[OFF_U0 + ii];
    float usn = ws[OFF_US + b * 256 + ii] + 4096.0f * u0;
#pragma unroll
    for (int j = 0; j < 4; ++j) {
      int jj = tj * 64 + tx * 4 + j;
      float v = (acc[i][j] + u0 * ws[OFF_VTS + b * 256 + jj] + usn * ws[OFF_TPB + jj]) * inv;
      if (ii == jj) v += 1.0f;
      A[ii * CC + jj] = v;
    }
  }
}

// ---- out = A_b @ x_b + bias' ----
__global__ __launch_bounds__(256) void k_out(const float* __restrict__ x,
                                             const float* __restrict__ ws,
                                             float* __restrict__ out) {
  __shared__ float As[32][LDSPAD], Bs[32][LDSPAD];
  int t = threadIdx.x, bid = blockIdx.x;
  int b = bid & 3;
  int pt = (bid >> 2) & 63;
  int it = bid >> 8;               // 0..3
  const float* Ab = ws + OFF_A + b * 65536;
  const float* xb = x + (size_t)b * CC * NSP;
  float acc[4][4] = {};
  int tx = t & 15, ty = t >> 4;
  for (int k0 = 0; k0 < 256; k0 += 32) {
    stage_t(Ab + (it * 64) * CC + k0, CC, As, t);
    stage_n(xb + k0 * NSP + pt * 64, NSP, Bs, t);
    __syncthreads();
    mac_tile(As, Bs, acc, tx, ty);
    __syncthreads();
  }
  const float* bias = ws + OFF_BIAS + b * 256;
  float* ob = out + (size_t)b * CC * NSP;
#pragma unroll
  for (int i = 0; i < 4; ++i) {
    int ii = it * 64 + ty * 4 + i;
    float bi = bias[ii];
#pragma unroll
    for (int j = 0; j < 4; ++j)
      ob[ii * NSP + pt * 64 + tx * 4 + j] = acc[i][j] + bi;
  }
}

extern "C" void kernel_launch(void* const* d_in, const int* in_sizes, int n_in,
                              void* d_out, int out_size, void* d_ws, size_t ws_size,
                              hipStream_t stream) {
  const float* x       = (const float*)d_in[0];
  const float* g_w     = (const float*)d_in[1];
  const float* g_b     = (const float*)d_in[2];
  const float* theta_w = (const float*)d_in[3];
  const float* theta_b = (const float*)d_in[4];
  const float* phi_w   = (const float*)d_in[5];
  const float* phi_b   = (const float*)d_in[6];
  const float* out_w   = (const float*)d_in[7];
  const float* out_b   = (const float*)d_in[8];
  float* ws  = (float*)d_ws;
  float* out = (float*)d_out;

  k_small0<<<dim3(513), dim3(256), 0, stream>>>(g_w, g_b, theta_w, theta_b,
                                                phi_w, phi_b, out_w, ws);
  k_rowsum<<<dim3(NB * 256), dim3(64), 0, stream>>>(x, ws);
  k_gram<<<dim3(512), dim3(256), 0, stream>>>(x, ws);
  k_gsum<<<dim3(1024), dim3(256), 0, stream>>>(ws);
  k_q<<<dim3(64), dim3(256), 0, stream>>>(ws);
  k_vec<<<dim3(NB), dim3(256), 0, stream>>>(ws, out_b);
  k_a<<<dim3(64), dim3(256), 0, stream>>>(ws);
  k_out<<<dim3(1024), dim3(256), 0, stream>>>(x, ws, out);
}

// Round 2
// 167.061 us; speedup vs baseline: 1.3764x; 1.3764x over previous
//
#include <hip/hip_runtime.h>
#include <hip/hip_bf16.h>

// Non-local block, algebraically collapsed to out_b = x_b + A'_b x_b + bias'_b,
// A'_b = (U G_b V + u0 (V^T s_b)^T + (U s_b + N u0) tpb^T)/N,  G_b = x_b x_b^T.
// All big matmuls on bf16 MFMA 16x16x32; residual + bias added in fp32.

#define CC   256
#define NSP  4096
#define NB   4
#define KSPLIT 16

typedef __attribute__((ext_vector_type(8))) short bf16x8;
typedef __attribute__((ext_vector_type(4))) float f32x4;

// ---------------- workspace layout ----------------
// fp32 region (float offsets from ws base)
#define F_P    0                         // [16][4][256][256] gram partials
#define F_Q    4194304                   // [4][256][256] Q = U@G
#define F_U    4456448                   // [256][256]
#define F_VT   4521984                   // [256][256]  VT[i][j] = V[j][i]
#define F_S    4587520                   // [4][256]
#define F_U0   4588544                   // [256]
#define F_WTB  4588800                   // [256]
#define F_TPB  4589056                   // [256]
#define F_C0   4589312                   // [1] (padded)
#define F_BIAS 4589568                   // [4][256]
#define F_END  4590592
// bf16 region (ushort offsets from (ws + F_END floats))
#define H_XH   0                         // [4][256][4096] bf16 x
#define H_XT   4194304                   // [4][4096][256] bf16 x^T
#define H_GH   8388608                   // [4][256][256]
#define H_UH   8650752                   // [256][256]
#define H_VHT  8716288                   // [256][256]
#define H_QH   8781824                   // [4][256][256]
#define H_AH   9043968                   // [4][256][256]

__device__ __forceinline__ unsigned short f2bf(float f) {
  __hip_bfloat16 h = __float2bfloat16(f);
  return __builtin_bit_cast(unsigned short, h);
}

__device__ __forceinline__ uint4 pack8(const unsigned short* h) {
  uint4 u;
  u.x = (unsigned)h[0] | ((unsigned)h[1] << 16);
  u.y = (unsigned)h[2] | ((unsigned)h[3] << 16);
  u.z = (unsigned)h[4] | ((unsigned)h[5] << 16);
  u.w = (unsigned)h[6] | ((unsigned)h[7] << 16);
  return u;
}

// Wave computes C[64x64] += A[64xK] * B^T[64xK] (both operands row-major with
// contiguous K). Register double-buffered, no LDS.
__device__ __forceinline__ void wave_gemm_bt(const unsigned short* __restrict__ A, int pitchA,
                                             const unsigned short* __restrict__ B, int pitchB,
                                             int K, int lane, f32x4 acc[4][4]) {
  int lm = lane & 15, lq = lane >> 4;
  const unsigned short* ap[4];
  const unsigned short* bp[4];
#pragma unroll
  for (int i = 0; i < 4; ++i) {
    ap[i] = A + (size_t)(i * 16 + lm) * pitchA + lq * 8;
    bp[i] = B + (size_t)(i * 16 + lm) * pitchB + lq * 8;
  }
  bf16x8 a0[4], b0[4];
#pragma unroll
  for (int i = 0; i < 4; ++i) {
    a0[i] = *(const bf16x8*)(ap[i]);
    b0[i] = *(const bf16x8*)(bp[i]);
  }
  for (int k = 32; k < K; k += 32) {
    bf16x8 a1[4], b1[4];
#pragma unroll
    for (int i = 0; i < 4; ++i) {
      a1[i] = *(const bf16x8*)(ap[i] + k);
      b1[i] = *(const bf16x8*)(bp[i] + k);
    }
#pragma unroll
    for (int mi = 0; mi < 4; ++mi)
#pragma unroll
      for (int ni = 0; ni < 4; ++ni)
        acc[mi][ni] = __builtin_amdgcn_mfma_f32_16x16x32_bf16(a0[mi], b0[ni], acc[mi][ni], 0, 0, 0);
#pragma unroll
    for (int i = 0; i < 4; ++i) { a0[i] = a1[i]; b0[i] = b1[i]; }
  }
#pragma unroll
  for (int mi = 0; mi < 4; ++mi)
#pragma unroll
    for (int ni = 0; ni < 4; ++ni)
      acc[mi][ni] = __builtin_amdgcn_mfma_f32_16x16x32_bf16(a0[mi], b0[ni], acc[mi][ni], 0, 0, 0);
}

// ---- K0: x-independent smalls: U, VT (fp32+bf16), u0/wtb/tpb/c0, zero s ----
__global__ __launch_bounds__(256) void k_init(
    const float* __restrict__ g_w, const float* __restrict__ g_b,
    const float* __restrict__ theta_w, const float* __restrict__ theta_b,
    const float* __restrict__ phi_w, const float* __restrict__ phi_b,
    const float* __restrict__ out_w, float* __restrict__ wsf,
    unsigned short* __restrict__ wsh) {
  int bid = blockIdx.x, t = threadIdx.x;
  if (bid < 256) {                 // U[i][j] = sum_k out_w[i][k] g_w[k][j]
    int i = bid;
    float acc = 0.f;
    for (int k = 0; k < 128; ++k) acc = fmaf(out_w[i * 128 + k], g_w[k * CC + t], acc);
    wsf[F_U + i * CC + t] = acc;
    wsh[H_UH + i * CC + t] = f2bf(acc);
  } else if (bid < 512) {          // VT[i][j] = V[j][i] = sum_k theta_w[k][i] phi_w[k][j]
    int i = bid - 256;
    float acc = 0.f;
    for (int k = 0; k < 128; ++k) acc = fmaf(theta_w[k * CC + i], phi_w[k * CC + t], acc);
    wsf[F_VT + i * CC + t] = acc;
    wsh[H_VHT + i * CC + t] = f2bf(acc);
  } else {
    float a0 = 0.f, a1 = 0.f, a2 = 0.f;
    for (int k = 0; k < 128; ++k) {
      a0 = fmaf(out_w[t * 128 + k], g_b[k], a0);
      a1 = fmaf(phi_w[k * CC + t], theta_b[k], a1);
      a2 = fmaf(theta_w[k * CC + t], phi_b[k], a2);
    }
    wsf[F_U0 + t]  = a0;
    wsf[F_WTB + t] = a1;
    wsf[F_TPB + t] = a2;
    if (t == 0) {
      float c = 0.f;
      for (int k = 0; k < 128; ++k) c = fmaf(phi_b[k], theta_b[k], c);
      wsf[F_C0] = c;
    }
#pragma unroll
    for (int q = 0; q < 4; ++q) wsf[F_S + q * 256 + t] = 0.f;
  }
}

// ---- prep: x -> xh (bf16), xT (bf16 transposed), rowsum atomics ----
__global__ __launch_bounds__(256) void k_prep(const float* __restrict__ x,
                                              float* __restrict__ wsf,
                                              unsigned short* __restrict__ wsh) {
  __shared__ float T[64][65];
  int bid = blockIdx.x;
  int nt = bid & 63, ct = (bid >> 6) & 3, b = bid >> 8;
  int c0 = ct * 64, n0 = nt * 64;
  int t = threadIdx.x;
  int r = t >> 2, j = t & 3;
  const float* xr = x + ((size_t)b * CC + c0 + r) * NSP + n0 + j * 16;
  float4 f0 = *(const float4*)(xr);
  float4 f1 = *(const float4*)(xr + 4);
  float4 f2 = *(const float4*)(xr + 8);
  float4 f3 = *(const float4*)(xr + 12);
  float v[16] = {f0.x, f0.y, f0.z, f0.w, f1.x, f1.y, f1.z, f1.w,
                 f2.x, f2.y, f2.z, f2.w, f3.x, f3.y, f3.z, f3.w};
  // rowsum partial (4 consecutive lanes per row)
  float p = 0.f;
#pragma unroll
  for (int i = 0; i < 16; ++i) p += v[i];
  p += __shfl_down(p, 1);
  p += __shfl_down(p, 2);
  if (j == 0) atomicAdd(&wsf[F_S + b * 256 + c0 + r], p);
  // bf16 x (same layout)
  unsigned short hs[16];
#pragma unroll
  for (int i = 0; i < 16; ++i) hs[i] = f2bf(v[i]);
  size_t xo = ((size_t)b * CC + c0 + r) * NSP + n0 + j * 16;
  *(uint4*)(wsh + H_XH + xo)     = pack8(hs);
  *(uint4*)(wsh + H_XH + xo + 8) = pack8(hs + 8);
  // LDS transpose
  *(float4*)&T[r][j * 16 + 0]  = f0;
  *(float4*)&T[r][j * 16 + 4]  = f1;
  *(float4*)&T[r][j * 16 + 8]  = f2;
  *(float4*)&T[r][j * 16 + 12] = f3;
  __syncthreads();
  int nr = t >> 2, j2 = t & 3;
  unsigned short o[16];
#pragma unroll
  for (int i = 0; i < 16; ++i) o[i] = f2bf(T[j2 * 16 + i][nr]);
  size_t to = ((size_t)b * NSP + n0 + nr) * CC + c0 + j2 * 16;
  *(uint4*)(wsh + H_XT + to)     = pack8(o);
  *(uint4*)(wsh + H_XT + to + 8) = pack8(o + 8);
}

// ---- Gram partials, split-K: P[ks][b] = xh_tile . xh_tile^T over K-chunk ----
__global__ __launch_bounds__(256) void k_gram(const unsigned short* __restrict__ wsh,
                                              float* __restrict__ wsf) {
  int bid = blockIdx.x;
  int ks = bid & 15, t4 = (bid >> 4) & 3, b = bid >> 6;
  int tm = t4 >> 1, tn = t4 & 1;
  int t = threadIdx.x, w = t >> 6, lane = t & 63;
  int wm = w >> 1, wn = w & 1;
  const unsigned short* xb = wsh + H_XH + (size_t)b * CC * NSP;
  const unsigned short* A = xb + (size_t)(tm * 128 + wm * 64) * NSP + ks * 256;
  const unsigned short* B = xb + (size_t)(tn * 128 + wn * 64) * NSP + ks * 256;
  f32x4 acc[4][4] = {};
  wave_gemm_bt(A, NSP, B, NSP, 256, lane, acc);
  float* P = wsf + F_P + (size_t)(ks * 4 + b) * 65536;
  int lm = lane & 15, lq = lane >> 4;
  int rb = tm * 128 + wm * 64, cb = tn * 128 + wn * 64;
#pragma unroll
  for (int mi = 0; mi < 4; ++mi)
#pragma unroll
    for (int rr = 0; rr < 4; ++rr) {
      int row = rb + mi * 16 + lq * 4 + rr;
#pragma unroll
      for (int ni = 0; ni < 4; ++ni)
        P[row * CC + cb + ni * 16 + lm] = acc[mi][ni][rr];
    }
}

// ---- reduce partials -> Gh bf16 ----
__global__ __launch_bounds__(256) void k_gsum(const float* __restrict__ wsf,
                                              unsigned short* __restrict__ wsh) {
  int idx = blockIdx.x * 256 + threadIdx.x;   // over [b][i][j] = 262144
  float a = 0.f;
#pragma unroll
  for (int ks = 0; ks < KSPLIT; ++ks) a += wsf[F_P + ks * 262144 + idx];
  wsh[H_GH + idx] = f2bf(a);
}

// ---- Q = Uh @ Gh (G symmetric -> B^T = G rows) ----
__global__ __launch_bounds__(256) void k_q(const unsigned short* __restrict__ wsh_c,
                                           float* __restrict__ wsf,
                                           unsigned short* __restrict__ wsh) {
  int bid = blockIdx.x;
  int b = bid >> 2, tm = (bid >> 1) & 1, tn = bid & 1;
  int t = threadIdx.x, w = t >> 6, lane = t & 63;
  int wm = w >> 1, wn = w & 1;
  const unsigned short* A = wsh_c + H_UH + (size_t)(tm * 128 + wm * 64) * CC;
  const unsigned short* B = wsh_c + H_GH + (size_t)b * 65536 + (size_t)(tn * 128 + wn * 64) * CC;
  f32x4 acc[4][4] = {};
  wave_gemm_bt(A, CC, B, CC, 256, lane, acc);
  int lm = lane & 15, lq = lane >> 4;
  int rb = tm * 128 + wm * 64, cb = tn * 128 + wn * 64;
#pragma unroll
  for (int mi = 0; mi < 4; ++mi)
#pragma unroll
    for (int rr = 0; rr < 4; ++rr) {
      int row = rb + mi * 16 + lq * 4 + rr;
#pragma unroll
      for (int ni = 0; ni < 4; ++ni) {
        int col = cb + ni * 16 + lm;
        float v = acc[mi][ni][rr];
        wsf[F_Q + (size_t)b * 65536 + row * CC + col] = v;
        wsh[H_QH + (size_t)b * 65536 + row * CC + col] = f2bf(v);
      }
    }
}

// ---- A' = (Qh @ VhT^T + u0 VTS^T + USN tpb^T)/N  (no +I), plus bias ----
__global__ __launch_bounds__(256) void k_a(const float* __restrict__ wsf,
                                           unsigned short* __restrict__ wsh,
                                           const float* __restrict__ out_b,
                                           float* __restrict__ wsf_mut) {
  __shared__ float sL[256], vtsL[128], usnL[128], qrL[128], red[256];
  int bid = blockIdx.x;
  int b = bid >> 2, tm = (bid >> 1) & 1, tn = bid & 1;
  int t = threadIdx.x, w = t >> 6, lane = t & 63;
  int wm = w >> 1, wn = w & 1;
  const float inv = 1.0f / 4096.0f;

  sL[t] = wsf[F_S + b * 256 + t];
  __syncthreads();
  {  // VTS[jl] = dot(VT[j], s), j = tn*128+jl
    int jl = t >> 1, half = t & 1;
    const float* vr = wsf + F_VT + (size_t)(tn * 128 + jl) * CC + half * 128;
    float p = 0.f;
    for (int kk = 0; kk < 128; ++kk) p = fmaf(vr[kk], sL[half * 128 + kk], p);
    red[t] = p;
  }
  __syncthreads();
  if ((t & 1) == 0) vtsL[t >> 1] = red[t] + red[t + 1];
  __syncthreads();
  {  // USN[il] = dot(U[i], s) + N*u0[i]
    int il = t >> 1, half = t & 1;
    int i = tm * 128 + il;
    const float* ur = wsf + F_U + (size_t)i * CC + half * 128;
    float p = 0.f;
    for (int kk = 0; kk < 128; ++kk) p = fmaf(ur[kk], sL[half * 128 + kk], p);
    red[t] = p;
  }
  __syncthreads();
  if ((t & 1) == 0) {
    int il = t >> 1;
    usnL[il] = red[t] + red[t + 1] + 4096.0f * wsf[F_U0 + tm * 128 + il];
  }
  __syncthreads();
  {  // qrow[il] = dot(Q[b][i], wtb)
    int il = t >> 1, half = t & 1;
    int i = tm * 128 + il;
    const float* qr = wsf + F_Q + (size_t)b * 65536 + (size_t)i * CC + half * 128;
    float p = 0.f;
    for (int kk = 0; kk < 128; ++kk) p = fmaf(qr[kk], wsf[F_WTB + half * 128 + kk], p);
    red[t] = p;
  }
  __syncthreads();
  if ((t & 1) == 0) qrL[t >> 1] = red[t] + red[t + 1];
  __syncthreads();
  red[t] = sL[t] * wsf[F_WTB + t];
  __syncthreads();
  for (int st = 128; st > 0; st >>= 1) {
    if (t < st) red[t] += red[t + st];
    __syncthreads();
  }
  float sw = red[0];
  float c0v = wsf[F_C0];
  if (tn == 0 && t < 128) {
    int i = tm * 128 + t;
    wsf_mut[F_BIAS + b * 256 + i] =
        (qrL[t] + wsf[F_U0 + i] * sw + usnL[t] * c0v) * inv + out_b[i];
  }

  const unsigned short* A = wsh + H_QH + (size_t)b * 65536 + (size_t)(tm * 128 + wm * 64) * CC;
  const unsigned short* B = wsh + H_VHT + (size_t)(tn * 128 + wn * 64) * CC;
  f32x4 acc[4][4] = {};
  wave_gemm_bt(A, CC, B, CC, 256, lane, acc);

  int lm = lane & 15, lq = lane >> 4;
#pragma unroll
  for (int mi = 0; mi < 4; ++mi)
#pragma unroll
    for (int rr = 0; rr < 4; ++rr) {
      int rl = wm * 64 + mi * 16 + lq * 4 + rr;
      int gi = tm * 128 + rl;
      float u0i = wsf[F_U0 + gi];
      float usn = usnL[rl];
#pragma unroll
      for (int ni = 0; ni < 4; ++ni) {
        int cl = wn * 64 + ni * 16 + lm;
        int gj = tn * 128 + cl;
        float v = (acc[mi][ni][rr] + u0i * vtsL[cl] + usn * wsf[F_TPB + gj]) * inv;
        wsh[H_AH + (size_t)b * 65536 + (size_t)gi * CC + gj] = f2bf(v);
      }
    }
}

// ---- out = x + Ah @ x (via xT) + bias ----
__global__ __launch_bounds__(256) void k_out(const unsigned short* __restrict__ wsh,
                                             const float* __restrict__ wsf,
                                             const float* __restrict__ x,
                                             float* __restrict__ out) {
  int bid = blockIdx.x;
  int b = bid >> 6, r6 = bid & 63;
  int tm = r6 >> 5, tn = r6 & 31;
  int t = threadIdx.x, w = t >> 6, lane = t & 63;
  int wm = w >> 1, wn = w & 1;
  const unsigned short* A = wsh + H_AH + (size_t)b * 65536 + (size_t)(tm * 128 + wm * 64) * CC;
  const unsigned short* B = wsh + H_XT + ((size_t)b * NSP + tn * 128 + wn * 64) * CC;
  f32x4 acc[4][4] = {};
  wave_gemm_bt(A, CC, B, CC, 256, lane, acc);
  int lm = lane & 15, lq = lane >> 4;
  int rb = tm * 128 + wm * 64, cb = tn * 128 + wn * 64;
#pragma unroll
  for (int mi = 0; mi < 4; ++mi)
#pragma unroll
    for (int rr = 0; rr < 4; ++rr) {
      int row = rb + mi * 16 + lq * 4 + rr;
      float bi = wsf[F_BIAS + b * 256 + row];
#pragma unroll
      for (int ni = 0; ni < 4; ++ni) {
        int col = cb + ni * 16 + lm;
        size_t off = ((size_t)b * CC + row) * NSP + col;
        out[off] = acc[mi][ni][rr] + x[off] + bi;
      }
    }
}

extern "C" void kernel_launch(void* const* d_in, const int* in_sizes, int n_in,
                              void* d_out, int out_size, void* d_ws, size_t ws_size,
                              hipStream_t stream) {
  const float* x       = (const float*)d_in[0];
  const float* g_w     = (const float*)d_in[1];
  const float* g_b     = (const float*)d_in[2];
  const float* theta_w = (const float*)d_in[3];
  const float* theta_b = (const float*)d_in[4];
  const float* phi_w   = (const float*)d_in[5];
  const float* phi_b   = (const float*)d_in[6];
  const float* out_w   = (const float*)d_in[7];
  const float* out_b   = (const float*)d_in[8];
  float* wsf = (float*)d_ws;
  unsigned short* wsh = (unsigned short*)(wsf + F_END);
  float* out = (float*)d_out;

  k_init<<<dim3(513), dim3(256), 0, stream>>>(g_w, g_b, theta_w, theta_b,
                                              phi_w, phi_b, out_w, wsf, wsh);
  k_prep<<<dim3(1024), dim3(256), 0, stream>>>(x, wsf, wsh);
  k_gram<<<dim3(256), dim3(256), 0, stream>>>(wsh, wsf);
  k_gsum<<<dim3(1024), dim3(256), 0, stream>>>(wsf, wsh);
  k_q<<<dim3(16), dim3(256), 0, stream>>>(wsh, wsf, wsh);
  k_a<<<dim3(16), dim3(256), 0, stream>>>(wsf, wsh, out_b, wsf);
  k_out<<<dim3(256), dim3(256), 0, stream>>>(wsh, wsf, x, out);
}